// Round 3
// baseline (112.757 us; speedup 1.0000x reference)
//
#include <hip/hip_runtime.h>

// ExplicitLiePE: y[b,s] = expm(A) @ x[b,s],  A = sum_k r[b,s,k] * 0.5*(L_k - L_k^T)
// (P_sp = identity in this config).
//
// TWO tokens per wave: lane i holds row i of 2*A/rho for token A (rowA[64]) and
// token B (rowB[64]); the two Clenshaw/Miller chains are interleaved.
//
// Round-3 change: the matvec broadcast of b1 is moved off the VALU. Previously
// each step did 128 v_readlane (half of all inner-loop VALU slots). Now each
// wave writes its (b1A,b1B) pair to a wave-private LDS slot (1 ds_write_b64)
// and reads it back with 32 ds_read_b128 at wave-uniform addresses (same-address
// LDS reads broadcast, conflict-free, and issue on the lgkm pipe, overlapping
// the fmacs). Same-wave DS ops execute in order, so no barrier/waitcnt hazards:
// step m's reads all precede step m+1's overwrite in program order.
// Accumulator mapping (a0<-j, a1<-j+1, a2<-j+2, a3<-j+3) is unchanged ->
// bit-identical numerics to round 2.
//
// Register control: amdgpu_waves_per_eu(1,2) — allocator budget down to 1 wave
// (no spill-for-occupancy; round 1 showed __launch_bounds__(TPB,2) spills the
// row arrays -> 330 MB of scratch traffic), scheduler target 2 waves/SIMD.

#define TPB 256
#define TOKENS_PER_BLOCK 8       // 4 waves x 2 tokens per wave
#define LPAD 66                  // row stride (floats): float2-aligned rows; both
                                 // row (2*lane+j banks) and col (consecutive-lane)
                                 // LDS reads are <=2-way (free)
#define LSTRIDE (64 * LPAD)

__global__ __launch_bounds__(TPB)
__attribute__((amdgpu_waves_per_eu(1, 2)))
void liepe_kernel(
    const float* __restrict__ x,
    const float* __restrict__ r_grid,
    const float* __restrict__ L_param,
    float* __restrict__ out,
    int n_tokens)
{
    __shared__ __align__(16) float Lsh[3 * LSTRIDE];
    __shared__ __align__(16) float2 bbuf[TPB / 64][64];   // per-wave b1 broadcast slot

    // Stage raw L (3x64x64) into LDS, padded stride. Coalesced global reads.
    for (int idx = threadIdx.x; idx < 3 * 64 * 64; idx += TPB) {
        int k = idx >> 12;
        int rem = idx & 4095;
        int i = rem >> 6;
        int j = rem & 63;
        Lsh[k * LSTRIDE + i * LPAD + j] = L_param[idx];
    }
    __syncthreads();

    const int lane = threadIdx.x & 63;
    const int wid  = threadIdx.x >> 6;
    const int bsA  = blockIdx.x * TOKENS_PER_BLOCK + wid * 2;
    if (bsA >= n_tokens) return;
    int bsB = bsA + 1;
    const bool hasB = (bsB < n_tokens);
    if (!hasB) bsB = bsA;

    float2* const bslot = bbuf[wid];

    const float rA0 = r_grid[bsA * 3 + 0];
    const float rA1 = r_grid[bsA * 3 + 1];
    const float rA2 = r_grid[bsA * 3 + 2];
    const float rB0 = r_grid[bsB * 3 + 0];
    const float rB1 = r_grid[bsB * 3 + 1];
    const float rB2 = r_grid[bsB * 3 + 2];

    const float sigA = 0.5f * (rA0 * rA0 + rA1 * rA1 + rA2 * rA2);
    const float sigB = 0.5f * (rB0 * rB0 + rB1 * rB1 + rB2 * rB2);
    const float rhoA = fmaf(17.3f, __builtin_sqrtf(sigA), 2.0f);
    const float rhoB = fmaf(17.3f, __builtin_sqrtf(sigB), 2.0f);
    const float invA = 1.0f / rhoA;
    const float invB = 1.0f / rhoB;
    const int   MA   = (int)rhoA + 14;   // >= ceil(rho)+13 -> tail ~1e-4
    const int   MB   = (int)rhoB + 14;
    const int   msA  = MA + 10;
    const int   msB  = MB + 10;

    const float cA0 = rA0 * invA, cA1 = rA1 * invA, cA2 = rA2 * invA;
    const float cB0 = rB0 * invB, cB1 = rB1 * invB, cB2 = rB2 * invB;

    // Build rows of 2A/rho for both tokens; the skew difference d = L[i][j]-L[j][i]
    // is token-independent -> LDS reads shared between A and B.
    float rowA[64], rowB[64];
    #pragma unroll
    for (int j2 = 0; j2 < 64; j2 += 2) {
        float aA0 = 0.f, aA1 = 0.f, aB0 = 0.f, aB1 = 0.f;
        #pragma unroll
        for (int k = 0; k < 3; ++k) {
            const float ckA = (k == 0) ? cA0 : ((k == 1) ? cA1 : cA2);
            const float ckB = (k == 0) ? cB0 : ((k == 1) ? cB1 : cB2);
            const float* base = &Lsh[k * LSTRIDE];
            float2 a = *(const float2*)(base + lane * LPAD + j2);   // row part
            float b0v = base[(j2 + 0) * LPAD + lane];               // col part
            float b1v = base[(j2 + 1) * LPAD + lane];
            float d0 = a.x - b0v;
            float d1 = a.y - b1v;
            aA0 = fmaf(ckA, d0, aA0);
            aA1 = fmaf(ckA, d1, aA1);
            aB0 = fmaf(ckB, d0, aB0);
            aB1 = fmaf(ckB, d1, aB1);
        }
        rowA[j2 + 0] = aA0; rowA[j2 + 1] = aA1;
        rowB[j2 + 0] = aB0; rowB[j2 + 1] = aB1;
    }

    const float xvA = x[bsA * 64 + lane];
    const float xvB = x[bsB * 64 + lane];

    const int maxM   = (MA > MB) ? MA : MB;
    const int mstart = maxM + 10;

    float jpA = 0.f, jcA = 0.f, NA = 0.f, b1A = 0.f, b2A = 0.f;
    float jpB = 0.f, jcB = 0.f, NB = 0.f, b1B = 0.f, b2B = 0.f;

    // ---- descent phase: Miller only, no matvec (all b's are exactly 0 here) ----
    #pragma unroll 1
    for (int m = mstart; m > maxM; --m) {
        if (m == msA) { jcA = 1e-12f; jpA = 0.f; NA = ((m & 1) == 0) ? 2e-12f : 0.f; }
        if (m == msB) { jcB = 1e-12f; jpB = 0.f; NB = ((m & 1) == 0) ? 2e-12f : 0.f; }
        const float twoM = 2.f * (float)m;
        float jmA = fmaf(twoM * invA, jcA, -jpA); jpA = jcA; jcA = jmA;
        float jmB = fmaf(twoM * invB, jcB, -jpB); jpB = jcB; jcB = jmB;
        const int mm = m - 1;
        if ((mm & 1) == 0) {
            NA += (mm > 0) ? (jmA + jmA) : jmA;
            NB += (mm > 0) ? (jmB + jmB) : jmB;
        }
    }

    // ---- main fused Miller+Clenshaw loop, both tokens interleaved ----
    #pragma unroll 1
    for (int m = maxM; m >= 1; --m) {
        if (m == msA) { jcA = 1e-12f; jpA = 0.f; NA = ((m & 1) == 0) ? 2e-12f : 0.f; }
        if (m == msB) { jcB = 1e-12f; jpB = 0.f; NB = ((m & 1) == 0) ? 2e-12f : 0.f; }

        // broadcast b1 via LDS: 1 ds_write_b64, then wave-uniform ds_read_b128s
        bslot[lane] = make_float2(b1A, b1B);

        float aA0 = 0.f, aA1 = 0.f, aA2 = 0.f, aA3 = 0.f;
        float aB0 = 0.f, aB1 = 0.f, aB2 = 0.f, aB3 = 0.f;
        #pragma unroll
        for (int j = 0; j < 64; j += 4) {
            float4 v0 = *(const float4*)&bslot[j + 0];   // (bA[j],bB[j],bA[j+1],bB[j+1])
            float4 v1 = *(const float4*)&bslot[j + 2];
            aA0 = fmaf(rowA[j + 0], v0.x, aA0);
            aB0 = fmaf(rowB[j + 0], v0.y, aB0);
            aA1 = fmaf(rowA[j + 1], v0.z, aA1);
            aB1 = fmaf(rowB[j + 1], v0.w, aB1);
            aA2 = fmaf(rowA[j + 2], v1.x, aA2);
            aB2 = fmaf(rowB[j + 2], v1.y, aB2);
            aA3 = fmaf(rowA[j + 3], v1.z, aA3);
            aB3 = fmaf(rowB[j + 3], v1.w, aB3);
        }
        float tA = (aA0 + aA1) + (aA2 + aA3);          // (2A/rho) b1, token A
        float tB = (aB0 + aB1) + (aB2 + aB3);

        float cfA = (m <= MA) ? (jcA + jcA) : 0.f;     // coefficient gate
        float cfB = (m <= MB) ? (jcB + jcB) : 0.f;
        float bnA = fmaf(cfA, xvA, tA + b2A);
        float bnB = fmaf(cfB, xvB, tB + b2B);
        b2A = b1A; b1A = bnA;
        b2B = b1B; b1B = bnB;

        const float twoM = 2.f * (float)m;
        float jmA = fmaf(twoM * invA, jcA, -jpA); jpA = jcA; jcA = jmA;
        float jmB = fmaf(twoM * invB, jcB, -jpB); jpB = jcB; jcB = jmB;
        const int mm = m - 1;
        if ((mm & 1) == 0) {
            NA += (mm > 0) ? (jmA + jmA) : jmA;
            NB += (mm > 0) ? (jmB + jmB) : jmB;
        }
    }

    // jc = J~_0 (already folded into N). Final: b0 = J~_0 x + (2A/rho)b1 + b2;
    // result = (b0 - (A/rho) b1) / N  -- reuse t = (2A/rho) b1.
    {
        bslot[lane] = make_float2(b1A, b1B);

        float aA0 = 0.f, aA1 = 0.f, aA2 = 0.f, aA3 = 0.f;
        float aB0 = 0.f, aB1 = 0.f, aB2 = 0.f, aB3 = 0.f;
        #pragma unroll
        for (int j = 0; j < 64; j += 4) {
            float4 v0 = *(const float4*)&bslot[j + 0];
            float4 v1 = *(const float4*)&bslot[j + 2];
            aA0 = fmaf(rowA[j + 0], v0.x, aA0);
            aB0 = fmaf(rowB[j + 0], v0.y, aB0);
            aA1 = fmaf(rowA[j + 1], v0.z, aA1);
            aB1 = fmaf(rowB[j + 1], v0.w, aB1);
            aA2 = fmaf(rowA[j + 2], v1.x, aA2);
            aB2 = fmaf(rowB[j + 2], v1.y, aB2);
            aA3 = fmaf(rowA[j + 3], v1.z, aA3);
            aB3 = fmaf(rowB[j + 3], v1.w, aB3);
        }
        float tA = (aA0 + aA1) + (aA2 + aA3);
        float tB = (aB0 + aB1) + (aB2 + aB3);
        float b0A = fmaf(jcA, xvA, tA + b2A);
        float b0B = fmaf(jcB, xvB, tB + b2B);
        float yA  = (b0A - 0.5f * tA) / NA;
        float yB  = (b0B - 0.5f * tB) / NB;
        out[bsA * 64 + lane] = yA;
        if (hasB) out[bsB * 64 + lane] = yB;
    }
}

extern "C" void kernel_launch(void* const* d_in, const int* in_sizes, int n_in,
                              void* d_out, int out_size, void* d_ws, size_t ws_size,
                              hipStream_t stream) {
    const float* x = (const float*)d_in[0];
    const float* r = (const float*)d_in[1];
    const float* L = (const float*)d_in[2];
    // d_in[3] = P_sp: identity (allow_mixing=False) -> R_eff = R_r.
    float* out = (float*)d_out;

    int n_tokens = in_sizes[0] / 64;  // B*S = 8192
    int grid = (n_tokens + TOKENS_PER_BLOCK - 1) / TOKENS_PER_BLOCK;
    liepe_kernel<<<grid, TPB, 0, stream>>>(x, r, L, out, n_tokens);
}

// Round 5
// 47.469 us; speedup vs baseline: 2.3754x; 2.3754x over previous
//
#include <hip/hip_runtime.h>

// ExplicitLiePE via MFMA: y[b,s] = expm(A) @ x[b,s], A = sum_k r_k * 0.5*(L_k - L_k^T).
//
// Rounds 0-3 established the VALU ceiling: the Clenshaw matvec's 64-wide broadcast
// costs ~50% of issue slots whether done by v_readlane (VALU, 92us) or LDS
// round-trip (DS-pipe-bound, 113us). The matrix core does broadcast+multiply in
// one op, and the per-token matrix is a shared-generator combination, so:
//
//   16 tokens per wave advance in lockstep; per step the matvec for all 16 is
//   G_k = (L_k - L_k^T) . B   (B = 64x16 block of b-vectors), k = 0..2
//   t[:,c] = sum_k (r_k[c]/rho_c) * G_k[:,c]
//
// computed with v_mfma_f32_16x16x32_f16. Precision: f16 hi/lo split of BOTH
// L' and b: L'.b ~= Lhi.bhi + Lhi.blo + Llo.bhi (dropped Llo.blo ~ 2^-24)
// -> f32-equivalent accuracy. Miller's unnormalized scale (up to ~1e14 for
// small rho) would overflow f16, so every step the whole state (jc,jp,N,b1,b2)
// is renormalized by s = jc>1 ? rcp(jc) : 1 -- the final y = (...)/N is
// scale-invariant, so any per-token scale is exact.
//
// Layout notes:
//  - C/D: reg r of lane l = D[16*m + (l>>4)*4 + r][l&15]  (HW-verified m89/m91).
//  - A/B k-slots: ANY bijection (g=l>>4, j) <-> k works as long as A and B use
//    the same one (the contraction is permutation-invariant); we use k = 8g+j.
//  - A row = l&15, B col = l&15 (standard CDNA fragment roles).
//  - b-block exchange D-layout -> B-layout goes through 4.6KB of wave-private
//    LDS: 8 ds_write_b64 + 4 ds_read_b128 per step (DS pipe has 4x headroom at
//    1 wave/SIMD; round-3's failure was 33 DS ops/step at 8 waves/CU).
//
// Round-4 fix: __builtin_amdgcn_cvt_pkrtz returns __fp16 ext_vector(2) --
// the union member must use that exact type (was _Float16-based, compile error).
//
// Prepass kernel builds the skew+split L fragments once into d_ws (48KB).

typedef _Float16 half8 __attribute__((ext_vector_type(8)));
typedef __fp16 fp16x2 __attribute__((ext_vector_type(2)));
typedef float float4t __attribute__((ext_vector_type(4)));

union H2U { fp16x2 h; unsigned u; };

__device__ __forceinline__ unsigned pkrtz2(float a, float b) {
    H2U v; v.h = __builtin_amdgcn_cvt_pkrtz(a, b); return v.u;
}
__device__ __forceinline__ float h2lo(unsigned u) { H2U v; v.u = u; return (float)v.h[0]; }
__device__ __forceinline__ float h2hi(unsigned u) { H2U v; v.u = u; return (float)v.h[1]; }

// ---------------- prepass: skew-symmetrize + f16 hi/lo split into fragments ----
// ws layout (f16): hi at [f*512 + l*8 + j], lo at +12288, f = (gen*4+m)*2+kt.
// Fragment element (l, j) of tile (gen, m, kt) = L'[16m + (l&15)][32kt + 8*(l>>4) + j].
__global__ void liepe_prep(const float* __restrict__ L, _Float16* __restrict__ wsA)
{
    int t = blockIdx.x * 256 + threadIdx.x;
    if (t >= 1536) return;
    int l   = t & 63;
    int f   = t >> 6;
    int kt  = f & 1;
    int m   = (f >> 1) & 3;
    int gen = f >> 3;
    int i   = 16 * m + (l & 15);
    int kk0 = 32 * kt + 8 * (l >> 4);
    const float* Lg = L + gen * 4096;
    half8 hi, lo;
    #pragma unroll
    for (int j = 0; j < 8; ++j) {
        int kk = kk0 + j;
        float d = Lg[i * 64 + kk] - Lg[kk * 64 + i];
        _Float16 h = (_Float16)d;
        hi[j] = h;
        lo[j] = (_Float16)(d - (float)h);
    }
    *(half8*)(wsA + f * 512 + l * 8) = hi;
    *(half8*)(wsA + 12288 + f * 512 + l * 8) = lo;
}

// ---------------- main kernel: 1 wave per block, 16 tokens per wave ------------

// GEMM over all 3 generators + hi/lo split products, combined with per-token q_k.
#define GEMM_COMBINE(TOUT)                                                         \
  {                                                                                \
    _Pragma("unroll")                                                              \
    for (int gen = 0; gen < 3; ++gen) {                                            \
      float q = (gen == 0) ? q0 : ((gen == 1) ? q1 : q2);                          \
      _Pragma("unroll")                                                            \
      for (int m2 = 0; m2 < 4; ++m2) {                                             \
        float4t ac = {0.f, 0.f, 0.f, 0.f};                                         \
        _Pragma("unroll")                                                          \
        for (int kt = 0; kt < 2; ++kt) {                                           \
          const int f = (gen * 4 + m2) * 2 + kt;                                   \
          ac = __builtin_amdgcn_mfma_f32_16x16x32_f16(Ah[f], Bh[kt], ac, 0, 0, 0); \
          ac = __builtin_amdgcn_mfma_f32_16x16x32_f16(Ah[f], Bl[kt], ac, 0, 0, 0); \
          ac = __builtin_amdgcn_mfma_f32_16x16x32_f16(Al[f], Bh[kt], ac, 0, 0, 0); \
        }                                                                          \
        _Pragma("unroll")                                                          \
        for (int r4 = 0; r4 < 4; ++r4) {                                           \
          if (gen == 0) TOUT[m2 * 4 + r4] = q * ac[r4];                            \
          else          TOUT[m2 * 4 + r4] = fmaf(q, ac[r4], TOUT[m2 * 4 + r4]);    \
        }                                                                          \
      }                                                                            \
    }                                                                              \
  }

// b1 (D-layout, 16 f32/lane) -> hi/lo f16 -> LDS -> B-fragments (k = 8g+j).
// Writer lane (c, g): dword D = 8*m2+2g holds b[2D], b[2D+1] of token c -> a
// linear f16 array per token; reader takes 4 consecutive dwords = k 8g..8g+7.
#define BCAST_B1()                                                                 \
  {                                                                                \
    _Pragma("unroll")                                                              \
    for (int m2 = 0; m2 < 4; ++m2) {                                               \
      unsigned h0 = pkrtz2(b1[4 * m2 + 0], b1[4 * m2 + 1]);                        \
      unsigned h1 = pkrtz2(b1[4 * m2 + 2], b1[4 * m2 + 3]);                        \
      unsigned l0 = pkrtz2(b1[4 * m2 + 0] - h2lo(h0), b1[4 * m2 + 1] - h2hi(h0));  \
      unsigned l1 = pkrtz2(b1[4 * m2 + 2] - h2lo(h1), b1[4 * m2 + 3] - h2hi(h1));  \
      const int di = c * 36 + 8 * m2 + 2 * g;                                      \
      *(uint2*)&bhiL[di] = make_uint2(h0, h1);                                     \
      *(uint2*)&bloL[di] = make_uint2(l0, l1);                                     \
    }                                                                              \
    _Pragma("unroll")                                                              \
    for (int kt = 0; kt < 2; ++kt) {                                               \
      Bh[kt] = *(const half8*)&bhiL[c * 36 + 16 * kt + 4 * g];                     \
      Bl[kt] = *(const half8*)&bloL[c * 36 + 16 * kt + 4 * g];                     \
    }                                                                              \
  }

__global__ __launch_bounds__(64, 1) void liepe_mfma(
    const float* __restrict__ x,
    const float* __restrict__ r_grid,
    const _Float16* __restrict__ wsA,
    float* __restrict__ out,
    int n_tokens)
{
    __shared__ __align__(16) unsigned bhiL[16 * 36];
    __shared__ __align__(16) unsigned bloL[16 * 36];

    const int lane = threadIdx.x;      // one wave per block
    const int c = lane & 15;           // token column
    const int g = lane >> 4;           // k-group / row sub-block

    int tok = blockIdx.x * 16 + c;
    if (tok >= n_tokens) tok = n_tokens - 1;

    // Resident A-fragments: 24 hi + 24 lo (192 VGPRs).
    half8 Ah[24], Al[24];
    #pragma unroll
    for (int f = 0; f < 24; ++f) {
        Ah[f] = *(const half8*)(wsA + f * 512 + lane * 8);
        Al[f] = *(const half8*)(wsA + 12288 + f * 512 + lane * 8);
    }

    // x in D-layout: xv[m2*4+r4] = x[tok][16*m2 + 4*g + r4].
    float xv[16];
    #pragma unroll
    for (int m2 = 0; m2 < 4; ++m2) {
        float4 v = *(const float4*)(x + tok * 64 + 16 * m2 + 4 * g);
        xv[4 * m2 + 0] = v.x; xv[4 * m2 + 1] = v.y;
        xv[4 * m2 + 2] = v.z; xv[4 * m2 + 3] = v.w;
    }

    const float r0 = r_grid[tok * 3 + 0];
    const float r1 = r_grid[tok * 3 + 1];
    const float r2 = r_grid[tok * 3 + 2];
    const float sig2 = 0.5f * (r0 * r0 + r1 * r1 + r2 * r2);
    const float rho  = fmaf(17.3f, __builtin_sqrtf(sig2), 2.0f);
    const float inv_rho = 1.0f / rho;
    const int   M  = (int)rho + 14;     // >= ceil(rho)+13 -> tail ~1e-4
    const int   ms = M + 10;
    const float q0 = r0 * inv_rho, q1 = r1 * inv_rho, q2 = r2 * inv_rho;

    // wave max degree
    int maxM = M;
    #pragma unroll
    for (int off = 1; off < 64; off <<= 1)
        maxM = max(maxM, __shfl_xor(maxM, off));

    float jp = 0.f, jc = 0.f, N = 0.f;
    float b1[16], b2[16];
    #pragma unroll
    for (int i = 0; i < 16; ++i) { b1[i] = 0.f; b2[i] = 0.f; }

    // ---- descent: Miller only (all b's exactly 0) ----
    #pragma unroll 1
    for (int m = maxM + 10; m > maxM; --m) {
        bool sd = (m == ms);
        jc = sd ? 1e-12f : jc;
        jp = sd ? 0.f : jp;
        N  = sd ? (((m & 1) == 0) ? 2e-12f : 0.f) : N;
        float s = (jc > 1.0f) ? __builtin_amdgcn_rcpf(jc) : 1.0f;
        jc *= s; jp *= s; N *= s;
        float jm = fmaf((2.f * (float)m) * inv_rho, jc, -jp);
        jp = jc; jc = jm;
        int mm = m - 1;
        if ((mm & 1) == 0) N += (mm > 0) ? (jm + jm) : jm;
    }

    half8 Bh[2], Bl[2];

    // ---- main fused Miller+Clenshaw loop ----
    #pragma unroll 1
    for (int m = maxM; m >= 1; --m) {
        bool sd = (m == ms);
        jc = sd ? 1e-12f : jc;
        jp = sd ? 0.f : jp;
        N  = sd ? (((m & 1) == 0) ? 2e-12f : 0.f) : N;

        // scale-invariant renormalization: keeps jc ~ O(1), b in f16 range
        float s = (jc > 1.0f) ? __builtin_amdgcn_rcpf(jc) : 1.0f;
        jc *= s; jp *= s; N *= s;
        #pragma unroll
        for (int i = 0; i < 16; ++i) { b1[i] *= s; b2[i] *= s; }

        BCAST_B1();

        float t[16];
        GEMM_COMBINE(t);

        float cf = (m <= M) ? (jc + jc) : 0.f;
        #pragma unroll
        for (int i = 0; i < 16; ++i) {
            float bn = fmaf(cf, xv[i], t[i] + b2[i]);
            b2[i] = b1[i];
            b1[i] = bn;
        }

        float jm = fmaf((2.f * (float)m) * inv_rho, jc, -jp);
        jp = jc; jc = jm;
        int mm = m - 1;
        if ((mm & 1) == 0) N += (mm > 0) ? (jm + jm) : jm;
    }

    // ---- final: b0 = J0*x + (2A/rho)b1 + b2;  y = (b0 - 0.5*(2A/rho)b1)/N ----
    {
        BCAST_B1();
        float t[16];
        GEMM_COMBINE(t);
        #pragma unroll
        for (int m2 = 0; m2 < 4; ++m2) {
            float4 v;
            float y0 = fmaf(jc, xv[4 * m2 + 0], t[4 * m2 + 0] + b2[4 * m2 + 0]);
            float y1 = fmaf(jc, xv[4 * m2 + 1], t[4 * m2 + 1] + b2[4 * m2 + 1]);
            float y2 = fmaf(jc, xv[4 * m2 + 2], t[4 * m2 + 2] + b2[4 * m2 + 2]);
            float y3 = fmaf(jc, xv[4 * m2 + 3], t[4 * m2 + 3] + b2[4 * m2 + 3]);
            v.x = (y0 - 0.5f * t[4 * m2 + 0]) / N;
            v.y = (y1 - 0.5f * t[4 * m2 + 1]) / N;
            v.z = (y2 - 0.5f * t[4 * m2 + 2]) / N;
            v.w = (y3 - 0.5f * t[4 * m2 + 3]) / N;
            *(float4*)(out + tok * 64 + 16 * m2 + 4 * g) = v;
        }
    }
}

extern "C" void kernel_launch(void* const* d_in, const int* in_sizes, int n_in,
                              void* d_out, int out_size, void* d_ws, size_t ws_size,
                              hipStream_t stream) {
    const float* x = (const float*)d_in[0];
    const float* r = (const float*)d_in[1];
    const float* L = (const float*)d_in[2];
    // d_in[3] = P_sp: identity (allow_mixing=False) -> R_eff = R_r.
    float* out = (float*)d_out;
    _Float16* wsA = (_Float16*)d_ws;   // 48KB: 24 hi + 24 lo fragments

    int n_tokens = in_sizes[0] / 64;   // B*S = 8192

    liepe_prep<<<6, 256, 0, stream>>>(L, wsA);

    int nwg = (n_tokens + 15) / 16;
    liepe_mfma<<<nwg, 64, 0, stream>>>(x, r, wsA, out, n_tokens);
}

// Round 6
// 32.107 us; speedup vs baseline: 3.5119x; 1.4785x over previous
//
#include <hip/hip_runtime.h>

// ExplicitLiePE via MFMA: y[b,s] = expm(A) @ x[b,s], A = sum_k r_k * 0.5*(L_k - L_k^T).
//
// Round-5 (one wave per 16-token group) reached 42us but OccupancyPercent=4.5%:
// 512 waves on 1024 SIMDs -> half the SIMDs idle, and each busy SIMD holds ONE
// wave with a serial step chain (stage->barrier-less read->MFMA->update), so
// ~70% of cycles were exposed latency (2240 cyc/step measured vs ~660 issued).
//
// Round-6: split the 64-row dimension across 4 waves per block. Block = one
// 16-token group; wave w owns D-rows [16w,16w+16) (the m2=w MFMA tile):
//   - A-fragments per wave: 6 hi + 6 lo (48 VGPRs)
//   - per step: stage own 16-row b1 slice as hi/lo f16 into double-buffered
//     LDS, ONE __syncthreads(), read full-K B fragments, 18 MFMAs, update.
//   - 2048 waves total -> 2 waves/SIMD on ALL SIMDs (TLP hides LDS+MFMA lat).
// Cross-wave correctness: all per-token scalar state (jc/jp/N, renorm s, cf,
// maxM) is computed redundantly and bit-identically in every wave, so the
// b-slices stay on one consistent scale. Double-buffer + 1 barrier/step is
// race-free: write@s+2 to buf is ordered after read@s by the barrier at s+1.
//
// Math (unchanged from round 5): 16 tokens/block advance in lockstep;
//   G_k = (L_k - L_k^T).B (B = 64x16 b-block), t[:,c] = sum_k (r_k[c]/rho_c) G_k[:,c]
// via v_mfma_f32_16x16x32_f16 with f16 hi/lo split of both L' and b
// (Lhi.bhi + Lhi.blo + Llo.bhi, dropped term ~2^-24). Miller's unnormalized
// scale is tamed by per-step renorm s = jc>1 ? rcp(jc) : 1 (y = (...)/N is
// scale-invariant).
//
// Layouts:
//  - C/D: reg r of lane l = D[16*m2 + (l>>4)*4 + r][l&15] (HW-verified m89/m91).
//  - A/B k-slot bijection k = 8*(l>>4)+j within each K=32 tile (consistent on
//    both sides -> contraction invariant).
//  - staging: stage[buf][hi/lo][token c][dword]; token stride 36 dwords
//    (b128-aligned reads at dword 16kt+4g).

typedef _Float16 half8 __attribute__((ext_vector_type(8)));
typedef __fp16 fp16x2 __attribute__((ext_vector_type(2)));
typedef float float4t __attribute__((ext_vector_type(4)));

union H2U { fp16x2 h; unsigned u; };

__device__ __forceinline__ unsigned pkrtz2(float a, float b) {
    H2U v; v.h = __builtin_amdgcn_cvt_pkrtz(a, b); return v.u;
}
__device__ __forceinline__ float h2lo(unsigned u) { H2U v; v.u = u; return (float)v.h[0]; }
__device__ __forceinline__ float h2hi(unsigned u) { H2U v; v.u = u; return (float)v.h[1]; }

// ---------------- prepass: skew-symmetrize + f16 hi/lo split into fragments ----
// ws layout (f16): hi at [f*512 + l*8 + j], lo at +12288, f = (gen*4+m2)*2+kt.
// Fragment element (l, j) of tile (gen, m2, kt) = L'[16m2 + (l&15)][32kt + 8*(l>>4) + j].
__global__ void liepe_prep(const float* __restrict__ L, _Float16* __restrict__ wsA)
{
    int t = blockIdx.x * 256 + threadIdx.x;
    if (t >= 1536) return;
    int l   = t & 63;
    int f   = t >> 6;
    int kt  = f & 1;
    int m   = (f >> 1) & 3;
    int gen = f >> 3;
    int i   = 16 * m + (l & 15);
    int kk0 = 32 * kt + 8 * (l >> 4);
    const float* Lg = L + gen * 4096;
    half8 hi, lo;
    #pragma unroll
    for (int j = 0; j < 8; ++j) {
        int kk = kk0 + j;
        float d = Lg[i * 64 + kk] - Lg[kk * 64 + i];
        _Float16 h = (_Float16)d;
        hi[j] = h;
        lo[j] = (_Float16)(d - (float)h);
    }
    *(half8*)(wsA + f * 512 + l * 8) = hi;
    *(half8*)(wsA + 12288 + f * 512 + l * 8) = lo;
}

// ---------------- main kernel: 4 waves per block, 16 tokens per block --------

#define PSTR 36   // token stride in dwords (b128-aligned reads; mild 2-way banks)

// stage own b1 slice (hi/lo f16), sync, load full-K B fragments, flip buffer.
#define STAGE_AND_LOAD_B()                                                       \
  {                                                                              \
    unsigned h0 = pkrtz2(b1[0], b1[1]);                                          \
    unsigned h1 = pkrtz2(b1[2], b1[3]);                                          \
    unsigned l0 = pkrtz2(b1[0] - h2lo(h0), b1[1] - h2hi(h0));                    \
    unsigned l1 = pkrtz2(b1[2] - h2lo(h1), b1[3] - h2hi(h1));                    \
    const int di = 8 * w + 2 * g;                                                \
    *(uint2*)&stage[buf][0][c][di] = make_uint2(h0, h1);                         \
    *(uint2*)&stage[buf][1][c][di] = make_uint2(l0, l1);                         \
    __syncthreads();                                                             \
    _Pragma("unroll")                                                            \
    for (int kt = 0; kt < 2; ++kt) {                                             \
      Bh[kt] = *(const half8*)&stage[buf][0][c][16 * kt + 4 * g];                \
      Bl[kt] = *(const half8*)&stage[buf][1][c][16 * kt + 4 * g];                \
    }                                                                            \
    buf ^= 1;                                                                    \
  }

// 18 MFMAs for this wave's 16-row tile; kt-split accumulators for 6 short
// independent chains; combine with per-token q_k into t[4].
#define GEMM_COMBINE(TOUT)                                                       \
  {                                                                              \
    _Pragma("unroll")                                                            \
    for (int gen = 0; gen < 3; ++gen) {                                          \
      float q = (gen == 0) ? q0 : ((gen == 1) ? q1 : q2);                        \
      float4t ac0 = {0.f, 0.f, 0.f, 0.f};                                        \
      float4t ac1 = {0.f, 0.f, 0.f, 0.f};                                        \
      ac0 = __builtin_amdgcn_mfma_f32_16x16x32_f16(Ah[gen*2+0], Bh[0], ac0, 0, 0, 0); \
      ac1 = __builtin_amdgcn_mfma_f32_16x16x32_f16(Ah[gen*2+1], Bh[1], ac1, 0, 0, 0); \
      ac0 = __builtin_amdgcn_mfma_f32_16x16x32_f16(Ah[gen*2+0], Bl[0], ac0, 0, 0, 0); \
      ac1 = __builtin_amdgcn_mfma_f32_16x16x32_f16(Ah[gen*2+1], Bl[1], ac1, 0, 0, 0); \
      ac0 = __builtin_amdgcn_mfma_f32_16x16x32_f16(Al[gen*2+0], Bh[0], ac0, 0, 0, 0); \
      ac1 = __builtin_amdgcn_mfma_f32_16x16x32_f16(Al[gen*2+1], Bh[1], ac1, 0, 0, 0); \
      _Pragma("unroll")                                                          \
      for (int r4 = 0; r4 < 4; ++r4) {                                           \
        float sum = ac0[r4] + ac1[r4];                                           \
        if (gen == 0) TOUT[r4] = q * sum;                                        \
        else          TOUT[r4] = fmaf(q, sum, TOUT[r4]);                         \
      }                                                                          \
    }                                                                            \
  }

__global__ __launch_bounds__(256) void liepe_mfma(
    const float* __restrict__ x,
    const float* __restrict__ r_grid,
    const _Float16* __restrict__ wsA,
    float* __restrict__ out,
    int n_tokens)
{
    __shared__ __align__(16) unsigned stage[2][2][16][PSTR];  // 18KB

    const int lane = threadIdx.x & 63;
    const int w    = threadIdx.x >> 6;   // row-slice / m2 tile, 0..3
    const int c    = lane & 15;          // token column
    const int g    = lane >> 4;          // k-group / row sub-block

    int tok = blockIdx.x * 16 + c;
    if (tok >= n_tokens) tok = n_tokens - 1;

    // A-fragments for this wave's row slice (m2 = w): 6 hi + 6 lo (48 VGPRs).
    half8 Ah[6], Al[6];
    #pragma unroll
    for (int gen = 0; gen < 3; ++gen) {
        #pragma unroll
        for (int kt = 0; kt < 2; ++kt) {
            const int f = (gen * 4 + w) * 2 + kt;
            Ah[gen * 2 + kt] = *(const half8*)(wsA + f * 512 + lane * 8);
            Al[gen * 2 + kt] = *(const half8*)(wsA + 12288 + f * 512 + lane * 8);
        }
    }

    // x slice in D-layout: xv[r4] = x[tok][16w + 4g + r4].
    float xv[4];
    {
        float4 v = *(const float4*)(x + tok * 64 + 16 * w + 4 * g);
        xv[0] = v.x; xv[1] = v.y; xv[2] = v.z; xv[3] = v.w;
    }

    // Per-token scalars — computed redundantly + identically in all 4 waves.
    const float r0 = r_grid[tok * 3 + 0];
    const float r1 = r_grid[tok * 3 + 1];
    const float r2 = r_grid[tok * 3 + 2];
    const float sig2 = 0.5f * (r0 * r0 + r1 * r1 + r2 * r2);
    const float rho  = fmaf(17.3f, __builtin_sqrtf(sig2), 2.0f);
    const float inv_rho = 1.0f / rho;
    const int   M  = (int)rho + 14;     // >= ceil(rho)+13 -> tail ~1e-4
    const int   ms = M + 10;
    const float q0 = r0 * inv_rho, q1 = r1 * inv_rho, q2 = r2 * inv_rho;

    // block max degree: wave-reduce suffices (every wave holds all 16 tokens).
    int maxM = M;
    #pragma unroll
    for (int off = 1; off < 64; off <<= 1)
        maxM = max(maxM, __shfl_xor(maxM, off));

    float jp = 0.f, jc = 0.f, N = 0.f;
    float b1[4] = {0.f, 0.f, 0.f, 0.f};
    float b2[4] = {0.f, 0.f, 0.f, 0.f};

    // ---- descent: Miller only (all b's exactly 0, no barriers needed) ----
    #pragma unroll 1
    for (int m = maxM + 10; m > maxM; --m) {
        bool sd = (m == ms);
        jc = sd ? 1e-12f : jc;
        jp = sd ? 0.f : jp;
        N  = sd ? (((m & 1) == 0) ? 2e-12f : 0.f) : N;
        float s = (jc > 1.0f) ? __builtin_amdgcn_rcpf(jc) : 1.0f;
        jc *= s; jp *= s; N *= s;
        float jm = fmaf((2.f * (float)m) * inv_rho, jc, -jp);
        jp = jc; jc = jm;
        int mm = m - 1;
        if ((mm & 1) == 0) N += (mm > 0) ? (jm + jm) : jm;
    }

    half8 Bh[2], Bl[2];
    int buf = 0;

    // ---- main fused Miller+Clenshaw loop (1 barrier per step, dbuf) ----
    #pragma unroll 1
    for (int m = maxM; m >= 1; --m) {
        bool sd = (m == ms);
        jc = sd ? 1e-12f : jc;
        jp = sd ? 0.f : jp;
        N  = sd ? (((m & 1) == 0) ? 2e-12f : 0.f) : N;

        // scale-invariant renorm: identical s in all 4 waves (same jc chain)
        float s = (jc > 1.0f) ? __builtin_amdgcn_rcpf(jc) : 1.0f;
        jc *= s; jp *= s; N *= s;
        #pragma unroll
        for (int i = 0; i < 4; ++i) { b1[i] *= s; b2[i] *= s; }

        STAGE_AND_LOAD_B();

        float t[4];
        GEMM_COMBINE(t);

        float cf = (m <= M) ? (jc + jc) : 0.f;
        #pragma unroll
        for (int i = 0; i < 4; ++i) {
            float bn = fmaf(cf, xv[i], t[i] + b2[i]);
            b2[i] = b1[i];
            b1[i] = bn;
        }

        float jm = fmaf((2.f * (float)m) * inv_rho, jc, -jp);
        jp = jc; jc = jm;
        int mm = m - 1;
        if ((mm & 1) == 0) N += (mm > 0) ? (jm + jm) : jm;
    }

    // ---- final: b0 = J0*x + (2A/rho)b1 + b2;  y = (b0 - 0.5*(2A/rho)b1)/N ----
    {
        STAGE_AND_LOAD_B();
        float t[4];
        GEMM_COMBINE(t);
        float4 v;
        float y0 = fmaf(jc, xv[0], t[0] + b2[0]);
        float y1 = fmaf(jc, xv[1], t[1] + b2[1]);
        float y2 = fmaf(jc, xv[2], t[2] + b2[2]);
        float y3 = fmaf(jc, xv[3], t[3] + b2[3]);
        v.x = (y0 - 0.5f * t[0]) / N;
        v.y = (y1 - 0.5f * t[1]) / N;
        v.z = (y2 - 0.5f * t[2]) / N;
        v.w = (y3 - 0.5f * t[3]) / N;
        *(float4*)(out + tok * 64 + 16 * w + 4 * g) = v;
    }
}

extern "C" void kernel_launch(void* const* d_in, const int* in_sizes, int n_in,
                              void* d_out, int out_size, void* d_ws, size_t ws_size,
                              hipStream_t stream) {
    const float* x = (const float*)d_in[0];
    const float* r = (const float*)d_in[1];
    const float* L = (const float*)d_in[2];
    // d_in[3] = P_sp: identity (allow_mixing=False) -> R_eff = R_r.
    float* out = (float*)d_out;
    _Float16* wsA = (_Float16*)d_ws;   // 48KB: 24 hi + 24 lo fragments

    int n_tokens = in_sizes[0] / 64;   // B*S = 8192

    liepe_prep<<<6, 256, 0, stream>>>(L, wsA);

    int nwg = (n_tokens + 15) / 16;
    liepe_mfma<<<nwg, 256, 0, stream>>>(x, r, wsA, out, n_tokens);
}